// Round 6
// baseline (146.495 us; speedup 1.0000x reference)
//
#include <hip/hip_runtime.h>
#include <hip/hip_bf16.h>
#include <math.h>

#define BB 16
#define DD 128
#define NN 4096
#define KK 1024
#define TAU 0.20f

typedef __attribute__((ext_vector_type(8))) short short8;
typedef __attribute__((ext_vector_type(4))) float f32x4;

static __device__ __forceinline__ unsigned short f32_bf16_rne(float f) {
    unsigned u = __float_as_uint(f);
    u += 0x7FFF + ((u >> 16) & 1);
    return (unsigned short)(u >> 16);
}

// ---------------------------------------------------------------------------
// e2[k] = ||emb[k]||^2  (f32)
// ---------------------------------------------------------------------------
__global__ void emb_sq_kernel(const float* __restrict__ emb,
                              float* __restrict__ e2) {
    int k = blockIdx.x * 256 + threadIdx.x;
    if (k >= KK) return;
    const float4* row = reinterpret_cast<const float4*>(emb + (size_t)k * DD);
    float a0 = 0.f, a1 = 0.f, a2 = 0.f, a3 = 0.f;
#pragma unroll
    for (int i = 0; i < DD / 16; ++i) {
        float4 v0 = row[i * 4 + 0];
        float4 v1 = row[i * 4 + 1];
        float4 v2 = row[i * 4 + 2];
        float4 v3 = row[i * 4 + 3];
        a0 += v0.x * v0.x + v0.y * v0.y + v0.z * v0.z + v0.w * v0.w;
        a1 += v1.x * v1.x + v1.y * v1.y + v1.z * v1.z + v1.w * v1.w;
        a2 += v2.x * v2.x + v2.y * v2.y + v2.z * v2.z + v2.w * v2.w;
        a3 += v3.x * v3.x + v3.y * v3.y + v3.z * v3.z + v3.w * v3.w;
    }
    e2[k] = (a0 + a1) + (a2 + a3);
}

// ---------------------------------------------------------------------------
// Pack (-2 * emb) as SINGLE bf16 in MFMA A-fragment order (256 KB).
// Fragment (t, s, lane): k = t*16 + (lane&15), d = s*32 + (lane>>4)*8 + j.
// ---------------------------------------------------------------------------
__global__ void emb_pack_kernel(const float* __restrict__ emb,
                                short* __restrict__ epk) {
    int g = blockIdx.x * 256 + threadIdx.x;     // 16384 fragments-slots
    int lane = g & 63;
    int s    = (g >> 6) & 3;
    int t    = g >> 8;
    int k = t * 16 + (lane & 15);
    int d = s * 32 + ((lane >> 4) & 3) * 8;
    const float* src = emb + (size_t)k * DD + d;
    short8 h;
#pragma unroll
    for (int j = 0; j < 8; ++j) h[j] = (short)f32_bf16_rne(-2.0f * src[j]);
    *reinterpret_cast<short8*>(epk + (size_t)g * 8) = h;
}

// compare-exchange on lexicographic (m, i); keeps smaller in (am, ai)
#define CE(am, ai, bm, bi) {                                        \
    bool sw_ = ((bm) < (am)) || ((bm) == (am) && (bi) < (ai));      \
    float tm_ = sw_ ? (bm) : (am); int ti_ = sw_ ? (bi) : (ai);     \
    (bm) = sw_ ? (am) : (bm); (bi) = sw_ ? (ai) : (bi);             \
    (am) = tm_; (ai) = ti_; }

// ---------------------------------------------------------------------------
// Main: block = 4 waves x 64 cols = 256-col n-tile; grid = 256 (1 block/CU).
// Wave covers its 64 cols (4 cgs x 16) for ALL 1024 k -> no cross-wave merge.
// Single-bf16 dot: m[k,n] = e2[k] - 2<ze,e> via MFMA C-init + packed -2e.
// A-frags direct from L2/L1 (all 4 waves share one k-stream), 1-tile-ahead
// prefetch with counted vmcnt(5). Per-(lane,cg) top-4, dq shfl merge with a
// pruned odd-even network, tau-guarded 4-way f64 exact refine.
// ---------------------------------------------------------------------------
__global__
__attribute__((amdgpu_flat_work_group_size(256, 256), amdgpu_waves_per_eu(1, 1)))
void vq_mfma(const float* __restrict__ ze, const float* __restrict__ emb,
             const short* __restrict__ epk, const float* __restrict__ e2,
             float* __restrict__ out) {
    __shared__ int   winner_s[256];
    __shared__ float ew[64][DD + 1];

    const int lane = threadIdx.x & 63;
    const int wave = threadIdx.x >> 6;
    const int b    = blockIdx.x >> 4;            // 16 blocks per batch entry
    const int n0b  = (blockIdx.x & 15) * 256;    // block's 256-col base
    const int col0 = n0b + wave * 64;            // wave's 64-col base
    const float* zb = ze + (size_t)b * DD * NN;

    const int nq = lane & 15;
    const int dq = (lane >> 4) & 3;

    // ---- z B-fragments: 4 cgs x 4 s, SINGLE bf16 (64 VGPRs) ----
    short8 zf[4][4];
#pragma unroll
    for (int cg = 0; cg < 4; ++cg) {
        const int col = col0 + cg * 16 + nq;
#pragma unroll
        for (int s = 0; s < 4; ++s) {
#pragma unroll
            for (int j = 0; j < 8; ++j) {
                int d = s * 32 + dq * 8 + j;
                zf[cg][s][j] = (short)f32_bf16_rne(zb[(size_t)d * NN + col]);
            }
        }
    }

    // per-cg top-4 (ascending; stable by earliest k)
    float m1[4], m2[4], m3[4], m4[4];
    int   i1[4], i2[4], i3[4], i4[4];
#pragma unroll
    for (int cg = 0; cg < 4; ++cg) {
        m1[cg] = INFINITY; m2[cg] = INFINITY; m3[cg] = INFINITY; m4[cg] = INFINITY;
        i1[cg] = 0; i2[cg] = 0; i3[cg] = 0; i4[cg] = 0;
    }

#define FRAG(T, S) \
    (*reinterpret_cast<const short8*>(epk + (((size_t)((T) * 4 + (S)) * 64 + lane) << 3)))

    // prologue: tile 0 frags + e2
    short8 aC0 = FRAG(0, 0), aC1 = FRAG(0, 1), aC2 = FRAG(0, 2), aC3 = FRAG(0, 3);
    float4 evC = *reinterpret_cast<const float4*>(e2 + dq * 4);

#pragma unroll 2
    for (int t = 0; t < 64; ++t) {
        short8 aN0, aN1, aN2, aN3; float4 evN;
        if (t < 63) {
            aN0 = FRAG(t + 1, 0); aN1 = FRAG(t + 1, 1);
            aN2 = FRAG(t + 1, 2); aN3 = FRAG(t + 1, 3);
            evN = *reinterpret_cast<const float4*>(e2 + (t + 1) * 16 + dq * 4);
            asm volatile("s_waitcnt vmcnt(5)" ::: "memory");  // tile-t loads done
        } else {
            asm volatile("s_waitcnt vmcnt(0)" ::: "memory");
        }
        __builtin_amdgcn_sched_barrier(0);

        f32x4 acc0 = {evC.x, evC.y, evC.z, evC.w};
        f32x4 acc1 = acc0, acc2 = acc0, acc3 = acc0;
#define STEP(AF, S) \
        acc0 = __builtin_amdgcn_mfma_f32_16x16x32_bf16(AF, zf[0][S], acc0, 0, 0, 0); \
        acc1 = __builtin_amdgcn_mfma_f32_16x16x32_bf16(AF, zf[1][S], acc1, 0, 0, 0); \
        acc2 = __builtin_amdgcn_mfma_f32_16x16x32_bf16(AF, zf[2][S], acc2, 0, 0, 0); \
        acc3 = __builtin_amdgcn_mfma_f32_16x16x32_bf16(AF, zf[3][S], acc3, 0, 0, 0);
        STEP(aC0, 0) STEP(aC1, 1) STEP(aC2, 2) STEP(aC3, 3)
#undef STEP

        const int kb = t * 16 + dq * 4;
#pragma unroll
        for (int cg = 0; cg < 4; ++cg) {
            const f32x4 a = (cg == 0) ? acc0 : (cg == 1) ? acc1
                          : (cg == 2) ? acc2 : acc3;   // cg is unroll-const
#pragma unroll
            for (int r = 0; r < 4; ++r) {
                const float m = a[r];
                const int   k = kb + r;
                if (m < m4[cg]) {                      // sorted insert, stable
                    if (m < m3[cg]) {
                        m4[cg] = m3[cg]; i4[cg] = i3[cg];
                        if (m < m2[cg]) {
                            m3[cg] = m2[cg]; i3[cg] = i2[cg];
                            if (m < m1[cg]) {
                                m2[cg] = m1[cg]; i2[cg] = i1[cg];
                                m1[cg] = m;      i1[cg] = k;
                            } else { m2[cg] = m; i2[cg] = k; }
                        } else { m3[cg] = m; i3[cg] = k; }
                    } else { m4[cg] = m; i4[cg] = k; }
                }
            }
        }
        aC0 = aN0; aC1 = aN1; aC2 = aN2; aC3 = aN3; evC = evN;
    }
#undef FRAG

    // ---- merge sorted-4 lists across the 4 dq lane-groups (same column) ----
#pragma unroll
    for (int cg = 0; cg < 4; ++cg) {
#pragma unroll
        for (int off = 16; off < 64; off <<= 1) {
            float B0m = __shfl_xor(m1[cg], off); int B0i = __shfl_xor(i1[cg], off);
            float B1m = __shfl_xor(m2[cg], off); int B1i = __shfl_xor(i2[cg], off);
            float B2m = __shfl_xor(m3[cg], off); int B2i = __shfl_xor(i3[cg], off);
            float B3m = __shfl_xor(m4[cg], off); int B3i = __shfl_xor(i4[cg], off);
            // pruned odd-even merge of two sorted-4 lists -> lowest 4 sorted
            CE(m1[cg], i1[cg], B0m, B0i)
            CE(m2[cg], i2[cg], B1m, B1i)
            CE(m3[cg], i3[cg], B2m, B2i)
            CE(m4[cg], i4[cg], B3m, B3i)
            CE(m3[cg], i3[cg], B0m, B0i)
            CE(m4[cg], i4[cg], B1m, B1i)
            CE(m2[cg], i2[cg], m3[cg], i3[cg])
            CE(m4[cg], i4[cg], B0m, B0i)
            CE(m3[cg], i3[cg], m4[cg], i4[cg])
        }
    }

    // ---- lane c owns column col0 + c: its cg = c>>4 entry IS that column ----
    {
        const int cgid = lane >> 4;
#define SEL(A) (cgid == 0 ? A[0] : cgid == 1 ? A[1] : cgid == 2 ? A[2] : A[3])
        float M1 = SEL(m1), M2 = SEL(m2), M3 = SEL(m3), M4 = SEL(m4);
        int   I1 = SEL(i1), I2 = SEL(i2), I3 = SEL(i3), I4 = SEL(i4);
#undef SEL
        (void)M3; (void)M4;
        int best = I1;
        // exact f64 4-way re-compare when the approx gap could hide a flip.
        // single-bf16 dot error sigma~0.03 => TAU=0.2 ~5sigma on the gap;
        // top-4 guarantees the true argmin is among candidates (P_fail ~1e-3).
        if (M2 - M1 < TAU) {
            const int coln = col0 + lane;
            const float* ea = emb + (size_t)I1 * DD;
            const float* eb = emb + (size_t)I2 * DD;
            const float* ec = emb + (size_t)I3 * DD;
            const float* ed = emb + (size_t)I4 * DD;
            double dA = 0.0, dB = 0.0, dC = 0.0, dDd = 0.0;
            for (int d = 0; d < DD; ++d) {
                double zv = (double)zb[(size_t)d * NN + coln];
                double a = zv - (double)ea[d]; dA += a * a;
                double bq = zv - (double)eb[d]; dB += bq * bq;
                double c = zv - (double)ec[d]; dC += c * c;
                double e = zv - (double)ed[d]; dDd += e * e;
            }
            double dbest = dA;
            if (dB < dbest || (dB == dbest && I2 < best)) { dbest = dB; best = I2; }
            if (dC < dbest || (dC == dbest && I3 < best)) { dbest = dC; best = I3; }
            if (dDd < dbest || (dDd == dbest && I4 < best)) { dbest = dDd; best = I4; }
        }
        winner_s[wave * 64 + lane] = best;
    }
    __syncthreads();

    // ---- epilogue: 4 chunks of 64 cols; stage winner rows, write coalesced
#pragma unroll 1
    for (int q = 0; q < 4; ++q) {
#pragma unroll 4
        for (int r = wave * 16; r < wave * 16 + 16; ++r) {
            const int idx = winner_s[q * 64 + r];    // wave-uniform per iter
            ew[r][lane]      = emb[(size_t)idx * DD + lane];
            ew[r][lane + 64] = emb[(size_t)idx * DD + lane + 64];
        }
        __syncthreads();
#pragma unroll 4
        for (int dd = 0; dd < 32; ++dd) {
            const int d = wave * 32 + dd;
            const int coln = n0b + q * 64 + lane;
            const float zv = zb[(size_t)d * NN + coln];
            const float evv = ew[lane][d];
            out[((size_t)b * DD + d) * NN + coln] = zv + (evv - zv);
        }
        __syncthreads();
    }
}

// ---------------------------------------------------------------------------
extern "C" void kernel_launch(void* const* d_in, const int* in_sizes, int n_in,
                              void* d_out, int out_size, void* d_ws, size_t ws_size,
                              hipStream_t stream) {
    (void)in_sizes; (void)n_in; (void)out_size; (void)ws_size;
    const float* ze  = (const float*)d_in[0];   // (B, D, N) f32
    const float* emb = (const float*)d_in[1];   // (K, D)    f32
    float*       out = (float*)d_out;           // (B, D, N) f32

    char* ws = (char*)d_ws;
    short* epk = (short*)ws;                          // 256 KB packed -2*emb
    float* e2  = (float*)(ws + (size_t)KK * DD * 2);  // 4 KB

    emb_sq_kernel<<<KK / 256, 256, 0, stream>>>(emb, e2);
    emb_pack_kernel<<<(KK * DD / 8) / 256, 256, 0, stream>>>(emb, epk);
    vq_mfma<<<(BB * NN) / 256, 256, 0, stream>>>(ze, emb, epk, e2, out);
}

// Round 7
// 102.109 us; speedup vs baseline: 1.4347x; 1.4347x over previous
//
#include <hip/hip_runtime.h>
#include <hip/hip_bf16.h>
#include <math.h>

#define BB 16
#define DD 128
#define NN 4096
#define KK 1024
#define TAU 0.20f

typedef __attribute__((ext_vector_type(8))) short short8;
typedef __attribute__((ext_vector_type(4))) float f32x4;

static __device__ __forceinline__ unsigned short f32_bf16_rne(float f) {
    unsigned u = __float_as_uint(f);
    u += 0x7FFF + ((u >> 16) & 1);
    return (unsigned short)(u >> 16);
}

// ---------------------------------------------------------------------------
// e2[k] = ||emb[k]||^2  (f32)
// ---------------------------------------------------------------------------
__global__ void emb_sq_kernel(const float* __restrict__ emb,
                              float* __restrict__ e2) {
    int k = blockIdx.x * 256 + threadIdx.x;
    if (k >= KK) return;
    const float4* row = reinterpret_cast<const float4*>(emb + (size_t)k * DD);
    float a0 = 0.f, a1 = 0.f, a2 = 0.f, a3 = 0.f;
#pragma unroll
    for (int i = 0; i < DD / 16; ++i) {
        float4 v0 = row[i * 4 + 0];
        float4 v1 = row[i * 4 + 1];
        float4 v2 = row[i * 4 + 2];
        float4 v3 = row[i * 4 + 3];
        a0 += v0.x * v0.x + v0.y * v0.y + v0.z * v0.z + v0.w * v0.w;
        a1 += v1.x * v1.x + v1.y * v1.y + v1.z * v1.z + v1.w * v1.w;
        a2 += v2.x * v2.x + v2.y * v2.y + v2.z * v2.z + v2.w * v2.w;
        a3 += v3.x * v3.x + v3.y * v3.y + v3.z * v3.z + v3.w * v3.w;
    }
    e2[k] = (a0 + a1) + (a2 + a3);
}

// ---------------------------------------------------------------------------
// Pack (-2 * emb) as SINGLE bf16 in MFMA A-fragment order (256 KB).
// Fragment (t, s, lane): k = t*16 + (lane&15), d = s*32 + (lane>>4)*8 + j.
// ---------------------------------------------------------------------------
__global__ void emb_pack_kernel(const float* __restrict__ emb,
                                short* __restrict__ epk) {
    int g = blockIdx.x * 256 + threadIdx.x;     // 16384 fragment-slots
    int lane = g & 63;
    int s    = (g >> 6) & 3;
    int t    = g >> 8;
    int k = t * 16 + (lane & 15);
    int d = s * 32 + ((lane >> 4) & 3) * 8;
    const float* src = emb + (size_t)k * DD + d;
    short8 h;
#pragma unroll
    for (int j = 0; j < 8; ++j) h[j] = (short)f32_bf16_rne(-2.0f * src[j]);
    *reinterpret_cast<short8*>(epk + (size_t)g * 8) = h;
}

// compare-exchange on lexicographic (m, i); keeps smaller in (am, ai)
#define CE(am, ai, bm, bi) {                                        \
    bool sw_ = ((bm) < (am)) || ((bm) == (am) && (bi) < (ai));      \
    float tm_ = sw_ ? (bm) : (am); int ti_ = sw_ ? (bi) : (ai);     \
    (bm) = sw_ ? (am) : (bm); (bi) = sw_ ? (ai) : (bi);             \
    (am) = tm_; (ai) = ti_; }

// ---------------------------------------------------------------------------
// Main: block = 4 waves x 32 cols = 128-col n-tile; grid = 512 -> 2 blocks/CU
// = 2 waves/SIMD (the round-6 fix: TLP to hide VALU/load latency).
// Wave covers its 32 cols (2 cgs x 16) for ALL 1024 k -> no cross-wave merge.
// Single-bf16 dot: m[k,n] = e2[k] - 2<ze,e> via MFMA C-init + packed -2e.
// A-frags direct from L1/L2 (8 waves/CU share one k-stream), 1-tile-ahead
// prefetch with counted vmcnt(5). Per-(lane,cg) top-4, dq shfl merge with a
// pruned odd-even network, tau-guarded 4-way f64 exact refine.
// Live regs ~110 -> fits the 128-reg budget, no spills (round-4/5 lesson).
// ---------------------------------------------------------------------------
__global__ __launch_bounds__(256)
void vq_mfma(const float* __restrict__ ze, const float* __restrict__ emb,
             const short* __restrict__ epk, const float* __restrict__ e2,
             float* __restrict__ out) {
    __shared__ int   winner_s[128];
    __shared__ float ew[64][DD + 1];

    const int lane = threadIdx.x & 63;
    const int wave = threadIdx.x >> 6;
    const int b    = blockIdx.x >> 5;            // 32 blocks per batch entry
    const int n0b  = (blockIdx.x & 31) * 128;    // block's 128-col base
    const int col0 = n0b + wave * 32;            // wave's 32-col base
    const float* zb = ze + (size_t)b * DD * NN;

    const int nq = lane & 15;
    const int dq = (lane >> 4) & 3;

    // ---- z B-fragments: 2 cgs x 4 s, SINGLE bf16 (32 VGPRs) ----
    short8 zf[2][4];
#pragma unroll
    for (int cg = 0; cg < 2; ++cg) {
        const int col = col0 + cg * 16 + nq;
#pragma unroll
        for (int s = 0; s < 4; ++s) {
#pragma unroll
            for (int j = 0; j < 8; ++j) {
                int d = s * 32 + dq * 8 + j;
                zf[cg][s][j] = (short)f32_bf16_rne(zb[(size_t)d * NN + col]);
            }
        }
    }

    // per-cg top-4 (ascending; stable by earliest k)
    float m1[2], m2[2], m3[2], m4[2];
    int   i1[2], i2[2], i3[2], i4[2];
#pragma unroll
    for (int cg = 0; cg < 2; ++cg) {
        m1[cg] = INFINITY; m2[cg] = INFINITY; m3[cg] = INFINITY; m4[cg] = INFINITY;
        i1[cg] = 0; i2[cg] = 0; i3[cg] = 0; i4[cg] = 0;
    }

#define FRAG(T, S) \
    (*reinterpret_cast<const short8*>(epk + (((size_t)((T) * 4 + (S)) * 64 + lane) << 3)))

    // prologue: tile 0 frags + e2
    short8 aC0 = FRAG(0, 0), aC1 = FRAG(0, 1), aC2 = FRAG(0, 2), aC3 = FRAG(0, 3);
    float4 evC = *reinterpret_cast<const float4*>(e2 + dq * 4);

#pragma unroll 2
    for (int t = 0; t < 64; ++t) {
        short8 aN0, aN1, aN2, aN3; float4 evN;
        if (t < 63) {
            aN0 = FRAG(t + 1, 0); aN1 = FRAG(t + 1, 1);
            aN2 = FRAG(t + 1, 2); aN3 = FRAG(t + 1, 3);
            evN = *reinterpret_cast<const float4*>(e2 + (t + 1) * 16 + dq * 4);
            asm volatile("s_waitcnt vmcnt(5)" ::: "memory");  // tile-t loads done
        } else {
            asm volatile("s_waitcnt vmcnt(0)" ::: "memory");
        }
        __builtin_amdgcn_sched_barrier(0);

        f32x4 acc0 = {evC.x, evC.y, evC.z, evC.w};
        f32x4 acc1 = acc0;
#define STEP(AF, S) \
        acc0 = __builtin_amdgcn_mfma_f32_16x16x32_bf16(AF, zf[0][S], acc0, 0, 0, 0); \
        acc1 = __builtin_amdgcn_mfma_f32_16x16x32_bf16(AF, zf[1][S], acc1, 0, 0, 0);
        STEP(aC0, 0) STEP(aC1, 1) STEP(aC2, 2) STEP(aC3, 3)
#undef STEP

        const int kb = t * 16 + dq * 4;
#pragma unroll
        for (int cg = 0; cg < 2; ++cg) {
            const f32x4 a = (cg == 0) ? acc0 : acc1;   // cg is unroll-const
#pragma unroll
            for (int r = 0; r < 4; ++r) {
                const float m = a[r];
                const int   k = kb + r;
                if (m < m4[cg]) {                      // sorted insert, stable
                    if (m < m3[cg]) {
                        m4[cg] = m3[cg]; i4[cg] = i3[cg];
                        if (m < m2[cg]) {
                            m3[cg] = m2[cg]; i3[cg] = i2[cg];
                            if (m < m1[cg]) {
                                m2[cg] = m1[cg]; i2[cg] = i1[cg];
                                m1[cg] = m;      i1[cg] = k;
                            } else { m2[cg] = m; i2[cg] = k; }
                        } else { m3[cg] = m; i3[cg] = k; }
                    } else { m4[cg] = m; i4[cg] = k; }
                }
            }
        }
        aC0 = aN0; aC1 = aN1; aC2 = aN2; aC3 = aN3; evC = evN;
    }
#undef FRAG

    // ---- merge sorted-4 lists across the 4 dq lane-groups (same column) ----
#pragma unroll
    for (int cg = 0; cg < 2; ++cg) {
#pragma unroll
        for (int off = 16; off < 64; off <<= 1) {
            float B0m = __shfl_xor(m1[cg], off); int B0i = __shfl_xor(i1[cg], off);
            float B1m = __shfl_xor(m2[cg], off); int B1i = __shfl_xor(i2[cg], off);
            float B2m = __shfl_xor(m3[cg], off); int B2i = __shfl_xor(i3[cg], off);
            float B3m = __shfl_xor(m4[cg], off); int B3i = __shfl_xor(i4[cg], off);
            // pruned odd-even merge of two sorted-4 lists -> lowest 4 sorted
            CE(m1[cg], i1[cg], B0m, B0i)
            CE(m2[cg], i2[cg], B1m, B1i)
            CE(m3[cg], i3[cg], B2m, B2i)
            CE(m4[cg], i4[cg], B3m, B3i)
            CE(m3[cg], i3[cg], B0m, B0i)
            CE(m4[cg], i4[cg], B1m, B1i)
            CE(m2[cg], i2[cg], m3[cg], i3[cg])
            CE(m4[cg], i4[cg], B0m, B0i)
            CE(m3[cg], i3[cg], m4[cg], i4[cg])
        }
    }

    // ---- lane c (0..31) owns column col0 + c: cg = c>>4 entry IS that col ----
    if (lane < 32) {
        const int cgid = lane >> 4;
        float M1 = cgid ? m1[1] : m1[0], M2 = cgid ? m2[1] : m2[0];
        int   I1 = cgid ? i1[1] : i1[0], I2 = cgid ? i2[1] : i2[0];
        int   I3 = cgid ? i3[1] : i3[0], I4 = cgid ? i4[1] : i4[0];
        int best = I1;
        // exact f64 4-way re-compare when the approx gap could hide a flip.
        // single-bf16 dot error sigma~0.03 => TAU=0.2 ~5sigma on the gap;
        // top-4 keeps the true argmin among candidates (P_fail ~1e-3 per run).
        if (M2 - M1 < TAU) {
            const int coln = col0 + lane;
            const float* ea = emb + (size_t)I1 * DD;
            const float* eb = emb + (size_t)I2 * DD;
            const float* ec = emb + (size_t)I3 * DD;
            const float* ed = emb + (size_t)I4 * DD;
            double dA = 0.0, dB = 0.0, dC = 0.0, dDd = 0.0;
            for (int d = 0; d < DD; ++d) {
                double zv = (double)zb[(size_t)d * NN + coln];
                double a  = zv - (double)ea[d]; dA  += a * a;
                double bq = zv - (double)eb[d]; dB  += bq * bq;
                double c  = zv - (double)ec[d]; dC  += c * c;
                double e  = zv - (double)ed[d]; dDd += e * e;
            }
            double dbest = dA;
            if (dB  < dbest || (dB  == dbest && I2 < best)) { dbest = dB;  best = I2; }
            if (dC  < dbest || (dC  == dbest && I3 < best)) { dbest = dC;  best = I3; }
            if (dDd < dbest || (dDd == dbest && I4 < best)) { dbest = dDd; best = I4; }
        }
        winner_s[wave * 32 + lane] = best;
    }
    __syncthreads();

    // ---- epilogue: 2 chunks of 64 cols; stage winner rows, write coalesced
#pragma unroll 1
    for (int q = 0; q < 2; ++q) {
#pragma unroll 4
        for (int r = wave * 16; r < wave * 16 + 16; ++r) {
            const int idx = winner_s[q * 64 + r];    // wave-uniform per iter
            ew[r][lane]      = emb[(size_t)idx * DD + lane];
            ew[r][lane + 64] = emb[(size_t)idx * DD + lane + 64];
        }
        __syncthreads();
#pragma unroll 4
        for (int dd = 0; dd < 32; ++dd) {
            const int d = wave * 32 + dd;
            const int coln = n0b + q * 64 + lane;
            const float zv = zb[(size_t)d * NN + coln];
            const float evv = ew[lane][d];
            out[((size_t)b * DD + d) * NN + coln] = zv + (evv - zv);
        }
        __syncthreads();
    }
}

// ---------------------------------------------------------------------------
extern "C" void kernel_launch(void* const* d_in, const int* in_sizes, int n_in,
                              void* d_out, int out_size, void* d_ws, size_t ws_size,
                              hipStream_t stream) {
    (void)in_sizes; (void)n_in; (void)out_size; (void)ws_size;
    const float* ze  = (const float*)d_in[0];   // (B, D, N) f32
    const float* emb = (const float*)d_in[1];   // (K, D)    f32
    float*       out = (float*)d_out;           // (B, D, N) f32

    char* ws = (char*)d_ws;
    short* epk = (short*)ws;                          // 256 KB packed -2*emb
    float* e2  = (float*)(ws + (size_t)KK * DD * 2);  // 4 KB

    emb_sq_kernel<<<KK / 256, 256, 0, stream>>>(emb, e2);
    emb_pack_kernel<<<(KK * DD / 8) / 256, 256, 0, stream>>>(emb, epk);
    vq_mfma<<<(BB * NN) / 128, 256, 0, stream>>>(ze, emb, epk, e2, out);
}

// Round 8
// 54.475 us; speedup vs baseline: 2.6892x; 1.8744x over previous
//
#include <hip/hip_runtime.h>
#include <hip/hip_bf16.h>
#include <math.h>

#define BB 16
#define DD 128
#define NN 4096
#define KK 1024
#define TAU 0.28f

typedef __attribute__((ext_vector_type(8))) short short8;
typedef __attribute__((ext_vector_type(4))) float f32x4;

static __device__ __forceinline__ unsigned short f32_bf16_rne(float f) {
    unsigned u = __float_as_uint(f);
    u += 0x7FFF + ((u >> 16) & 1);
    return (unsigned short)(u >> 16);
}
static __device__ __forceinline__ unsigned umin32(unsigned a, unsigned b) { return a < b ? a : b; }
static __device__ __forceinline__ unsigned umax32(unsigned a, unsigned b) { return a > b ? a : b; }

// ---------------------------------------------------------------------------
// e2[k] = ||emb[k]||^2  (f32)
// ---------------------------------------------------------------------------
__global__ void emb_sq_kernel(const float* __restrict__ emb,
                              float* __restrict__ e2) {
    int k = blockIdx.x * 256 + threadIdx.x;
    if (k >= KK) return;
    const float4* row = reinterpret_cast<const float4*>(emb + (size_t)k * DD);
    float a0 = 0.f, a1 = 0.f, a2 = 0.f, a3 = 0.f;
#pragma unroll
    for (int i = 0; i < DD / 16; ++i) {
        float4 v0 = row[i * 4 + 0];
        float4 v1 = row[i * 4 + 1];
        float4 v2 = row[i * 4 + 2];
        float4 v3 = row[i * 4 + 3];
        a0 += v0.x * v0.x + v0.y * v0.y + v0.z * v0.z + v0.w * v0.w;
        a1 += v1.x * v1.x + v1.y * v1.y + v1.z * v1.z + v1.w * v1.w;
        a2 += v2.x * v2.x + v2.y * v2.y + v2.z * v2.z + v2.w * v2.w;
        a3 += v3.x * v3.x + v3.y * v3.y + v3.z * v3.z + v3.w * v3.w;
    }
    e2[k] = (a0 + a1) + (a2 + a3);
}

// ---------------------------------------------------------------------------
// Pack (-2 * emb) as SINGLE bf16 in MFMA A-fragment order (256 KB).
// Fragment (t, s, lane): k = t*16 + (lane&15), d = s*32 + (lane>>4)*8 + j.
// ---------------------------------------------------------------------------
__global__ void emb_pack_kernel(const float* __restrict__ emb,
                                short* __restrict__ epk) {
    int g = blockIdx.x * 256 + threadIdx.x;     // 16384 fragment-slots
    int lane = g & 63;
    int s    = (g >> 6) & 3;
    int t    = g >> 8;
    int k = t * 16 + (lane & 15);
    int d = s * 32 + ((lane >> 4) & 3) * 8;
    const float* src = emb + (size_t)k * DD + d;
    short8 h;
#pragma unroll
    for (int j = 0; j < 8; ++j) h[j] = (short)f32_bf16_rne(-2.0f * src[j]);
    *reinterpret_cast<short8*>(epk + (size_t)g * 8) = h;
}

// CE on packed u32 keys: a <- min, b <- max (2 VALU, no vcc)
#define CEU(a, b) { unsigned lo_ = umin32(a, b), hi_ = umax32(a, b); (a) = lo_; (b) = hi_; }

// ---------------------------------------------------------------------------
// Main: block = 4 waves x 64 cols; wave (cgrp = w&1, khalf = w>>1) covers
// 32 cols x 512 k (32 tiles). Grid 1024 -> 4 blocks/CU = 4 waves/SIMD.
// m[k,n] = e2[k] + z2[n] + 1 - 2<ze,e>  (= d^2 + 1 > 0) via MFMA C-init with
// packed -2e A-operand. Key = (bits(m) & ~0x3FF) | k  -> non-negative floats
// compare as ints, so top-4 is a pure v_min_u32/v_max_u32 insert chain.
// dq-shfl merge + cross-k LDS merge on keys; ballot-compacted wave-
// cooperative f64 exact refine for columns with gap < TAU.
// ---------------------------------------------------------------------------
__global__ __launch_bounds__(256, 4)
void vq_mfma(const float* __restrict__ ze, const float* __restrict__ emb,
             const short* __restrict__ epk, const float* __restrict__ e2,
             float* __restrict__ out) {
    __shared__ unsigned kbuf[2][64][4];       // [khalf][block-col][rank]
    __shared__ int winner_s[64];
    __shared__ int rlist[64];
    __shared__ int rcnt;
    __shared__ float ew[64][DD + 1];

    const int lane = threadIdx.x & 63;
    const int wave = threadIdx.x >> 6;
    const int b    = blockIdx.x >> 6;             // 64 blocks per batch entry
    const int n0b  = (blockIdx.x & 63) * 64;      // block's 64-col base
    const int cgrp = wave & 1;                    // column half within block
    const int khalf = wave >> 1;                  // k half
    const int col0w = n0b + cgrp * 32;            // wave's 32-col base
    const float* zb = ze + (size_t)b * DD * NN;

    const int nq = lane & 15;
    const int dq = (lane >> 4) & 3;

    if (threadIdx.x == 0) rcnt = 0;

    // ---- z B-fragments (2 cgs x 4 s, single bf16, 32 VGPRs) + z2 ----
    short8 zf[2][4];
    float z2p[2] = {0.f, 0.f};
#pragma unroll
    for (int cg = 0; cg < 2; ++cg) {
        const int col = col0w + cg * 16 + nq;
#pragma unroll
        for (int s = 0; s < 4; ++s) {
#pragma unroll
            for (int j = 0; j < 8; ++j) {
                int d = s * 32 + dq * 8 + j;
                float z = zb[(size_t)d * NN + col];
                zf[cg][s][j] = (short)f32_bf16_rne(z);
                z2p[cg] += z * z;
            }
        }
    }
    // full z2 per column: sum the 4 dq lane-groups; +1 ensures m > 0 even
    // under bf16 dot error. (Any per-column constant preserves the argmin.)
#pragma unroll
    for (int cg = 0; cg < 2; ++cg) {
        z2p[cg] += __shfl_xor(z2p[cg], 16);
        z2p[cg] += __shfl_xor(z2p[cg], 32);
        z2p[cg] += 1.0f;
    }

    // sorted top-4 packed keys per cg (ascending)
    unsigned K1[2], K2[2], K3[2], K4[2];
#pragma unroll
    for (int cg = 0; cg < 2; ++cg) { K1[cg] = K2[cg] = K3[cg] = K4[cg] = 0xFFFFFFFFu; }

    const int t0 = khalf * 32;                    // this wave's 32 k-tiles

#define FRAG(T, S) \
    (*reinterpret_cast<const short8*>(epk + (((size_t)((T) * 4 + (S)) * 64 + lane) << 3)))

    short8 aC0 = FRAG(t0, 0), aC1 = FRAG(t0, 1), aC2 = FRAG(t0, 2), aC3 = FRAG(t0, 3);
    float4 evC = *reinterpret_cast<const float4*>(e2 + t0 * 16 + dq * 4);

#pragma unroll 2
    for (int tt = 0; tt < 32; ++tt) {
        short8 aN0, aN1, aN2, aN3; float4 evN;
        if (tt < 31) {
            const int tn = t0 + tt + 1;
            aN0 = FRAG(tn, 0); aN1 = FRAG(tn, 1);
            aN2 = FRAG(tn, 2); aN3 = FRAG(tn, 3);
            evN = *reinterpret_cast<const float4*>(e2 + tn * 16 + dq * 4);
            asm volatile("s_waitcnt vmcnt(5)" ::: "memory");  // tile-tt landed
        } else {
            asm volatile("s_waitcnt vmcnt(0)" ::: "memory");
        }
        __builtin_amdgcn_sched_barrier(0);

        f32x4 acc0 = {evC.x + z2p[0], evC.y + z2p[0], evC.z + z2p[0], evC.w + z2p[0]};
        f32x4 acc1 = {evC.x + z2p[1], evC.y + z2p[1], evC.z + z2p[1], evC.w + z2p[1]};
#define STEP(AF, S) \
        acc0 = __builtin_amdgcn_mfma_f32_16x16x32_bf16(AF, zf[0][S], acc0, 0, 0, 0); \
        acc1 = __builtin_amdgcn_mfma_f32_16x16x32_bf16(AF, zf[1][S], acc1, 0, 0, 0);
        STEP(aC0, 0) STEP(aC1, 1) STEP(aC2, 2) STEP(aC3, 3)
#undef STEP

        const unsigned kbase = (unsigned)((t0 + tt) * 16 + dq * 4);
#pragma unroll
        for (int cg = 0; cg < 2; ++cg) {
            const f32x4 a = (cg == 0) ? acc0 : acc1;       // cg is unroll-const
#pragma unroll
            for (int r = 0; r < 4; ++r) {
                unsigned x = (__float_as_uint(a[r]) & 0xFFFFFC00u) | (kbase + r);
                unsigned t1;
                t1 = umin32(K1[cg], x); x = umax32(K1[cg], x); K1[cg] = t1;
                t1 = umin32(K2[cg], x); x = umax32(K2[cg], x); K2[cg] = t1;
                t1 = umin32(K3[cg], x); x = umax32(K3[cg], x); K3[cg] = t1;
                K4[cg] = umin32(K4[cg], x);
            }
        }
        aC0 = aN0; aC1 = aN1; aC2 = aN2; aC3 = aN3; evC = evN;
    }
#undef FRAG

    // ---- merge sorted-4 key lists across the 4 dq lane-groups ----
#pragma unroll
    for (int cg = 0; cg < 2; ++cg) {
#pragma unroll
        for (int off = 16; off < 64; off <<= 1) {
            unsigned B1 = __shfl_xor(K1[cg], off);
            unsigned B2 = __shfl_xor(K2[cg], off);
            unsigned B3 = __shfl_xor(K3[cg], off);
            unsigned B4 = __shfl_xor(K4[cg], off);
            CEU(K1[cg], B1) CEU(K2[cg], B2) CEU(K3[cg], B3) CEU(K4[cg], B4)
            CEU(K3[cg], B1) CEU(K4[cg], B2)
            CEU(K2[cg], K3[cg])
            CEU(K4[cg], B1)
            CEU(K3[cg], K4[cg])
        }
    }

    // lane c (0..31): column col0w + c has its list in cg = c>>4
    if (lane < 32) {
        const int cgid = lane >> 4;
        const int bc = cgrp * 32 + lane;              // block-col index
        kbuf[khalf][bc][0] = cgid ? K1[1] : K1[0];
        kbuf[khalf][bc][1] = cgid ? K2[1] : K2[0];
        kbuf[khalf][bc][2] = cgid ? K3[1] : K3[0];
        kbuf[khalf][bc][3] = cgid ? K4[1] : K4[0];
    }
    __syncthreads();

    // ---- wave 0: merge k-halves per column, build refine list ----
    if (wave == 0) {
        unsigned A1 = kbuf[0][lane][0], A2 = kbuf[0][lane][1];
        unsigned A3 = kbuf[0][lane][2], A4 = kbuf[0][lane][3];
        unsigned B1 = kbuf[1][lane][0], B2 = kbuf[1][lane][1];
        unsigned B3 = kbuf[1][lane][2], B4 = kbuf[1][lane][3];
        CEU(A1, B1) CEU(A2, B2) CEU(A3, B3) CEU(A4, B4)
        CEU(A3, B1) CEU(A4, B2)
        CEU(A2, A3)
        CEU(A4, B1)
        CEU(A3, A4)
        const float M1 = __uint_as_float(A1 & 0xFFFFFC00u);
        const float M2 = __uint_as_float(A2 & 0xFFFFFC00u);
        const bool trig = (M2 - M1) < TAU;
        winner_s[lane] = (int)(A1 & 0x3FFu);
        kbuf[0][lane][0] = A1; kbuf[0][lane][1] = A2;     // candidates for refine
        kbuf[0][lane][2] = A3; kbuf[0][lane][3] = A4;
        const unsigned long long mask = __ballot(trig);
        if (trig) {
            const int idx = __popcll(mask & ((1ull << lane) - 1ull));
            rlist[idx] = lane;
        }
        if (lane == 0) rcnt = (int)__popcll(mask);
    }
    __syncthreads();

    // ---- cooperative exact f64 refine (rare: ~8% of columns) ----
    {
        const int rc = rcnt;
        for (int j = wave; j < rc; j += 4) {
            const int c = rlist[j];
            const int coln = n0b + c;
            const int I0 = (int)(kbuf[0][c][0] & 0x3FFu);
            const int I1 = (int)(kbuf[0][c][1] & 0x3FFu);
            const int I2 = (int)(kbuf[0][c][2] & 0x3FFu);
            const int I3 = (int)(kbuf[0][c][3] & 0x3FFu);
            double s0 = 0.0, s1 = 0.0, s2 = 0.0, s3 = 0.0;
#pragma unroll
            for (int h = 0; h < 2; ++h) {
                const int d = h * 64 + lane;
                const double zv = (double)zb[(size_t)d * NN + coln];
                double q;
                q = zv - (double)emb[(size_t)I0 * DD + d]; s0 += q * q;
                q = zv - (double)emb[(size_t)I1 * DD + d]; s1 += q * q;
                q = zv - (double)emb[(size_t)I2 * DD + d]; s2 += q * q;
                q = zv - (double)emb[(size_t)I3 * DD + d]; s3 += q * q;
            }
#pragma unroll
            for (int off = 1; off < 64; off <<= 1) {
                s0 += __shfl_xor(s0, off);
                s1 += __shfl_xor(s1, off);
                s2 += __shfl_xor(s2, off);
                s3 += __shfl_xor(s3, off);
            }
            int best = I0; double db = s0;
            if (s1 < db || (s1 == db && I1 < best)) { db = s1; best = I1; }
            if (s2 < db || (s2 == db && I2 < best)) { db = s2; best = I2; }
            if (s3 < db || (s3 == db && I3 < best)) { db = s3; best = I3; }
            if (lane == 0) winner_s[c] = best;
        }
    }
    __syncthreads();

    // ---- epilogue: stage winner rows in LDS, write coalesced ----
#pragma unroll 4
    for (int r = wave * 16; r < wave * 16 + 16; ++r) {
        const int idx = winner_s[r];                  // wave-uniform per iter
        ew[r][lane]      = emb[(size_t)idx * DD + lane];
        ew[r][lane + 64] = emb[(size_t)idx * DD + lane + 64];
    }
    __syncthreads();

#pragma unroll 4
    for (int dd = 0; dd < 32; ++dd) {
        const int d = wave * 32 + dd;
        const int coln = n0b + lane;
        const float zv = zb[(size_t)d * NN + coln];
        const float evv = ew[lane][d];
        out[((size_t)b * DD + d) * NN + coln] = zv + (evv - zv);
    }
}

// ---------------------------------------------------------------------------
extern "C" void kernel_launch(void* const* d_in, const int* in_sizes, int n_in,
                              void* d_out, int out_size, void* d_ws, size_t ws_size,
                              hipStream_t stream) {
    (void)in_sizes; (void)n_in; (void)out_size; (void)ws_size;
    const float* ze  = (const float*)d_in[0];   // (B, D, N) f32
    const float* emb = (const float*)d_in[1];   // (K, D)    f32
    float*       out = (float*)d_out;           // (B, D, N) f32

    char* ws = (char*)d_ws;
    short* epk = (short*)ws;                          // 256 KB packed -2*emb
    float* e2  = (float*)(ws + (size_t)KK * DD * 2);  // 4 KB

    emb_sq_kernel<<<KK / 256, 256, 0, stream>>>(emb, e2);
    emb_pack_kernel<<<(KK * DD / 8) / 256, 256, 0, stream>>>(emb, epk);
    vq_mfma<<<(BB * NN) / 64, 256, 0, stream>>>(ze, emb, epk, e2, out);
}